// Round 1
// baseline (1181.065 us; speedup 1.0000x reference)
//
#include <hip/hip_runtime.h>
#include <stdint.h>

typedef unsigned int u32;
typedef unsigned long long u64;

#define NB 16
#define NA 16384
#define KD 128
#define NM 524288

// output offsets (floats)
#define OFF_Y    0
#define OFF_YHAT 16
#define OFF_SM   32
#define OFF_CLS  4128
#define OFF_LOC  4129
#define OFF_Q    4130
#define OFF_KEYS 6178
#define OFF_VALS 67115042
#define OFF_AGE  67639330

// ws offsets (bytes)
#define WS_SAMPLES 0        // 16*128 f32
#define WS_NUMPOS  8192     // 16 f32
#define WS_YMAX    8256     // 16 i32
#define WS_LOCSUM  8320     // 1 f32
#define WS_QUERY   8384     // 16*128 f32
#define WS_ROWLOSS 16576    // 16 f32
#define WS_YHATIDX 16640    // 16 i32
#define WS_RESULT  16768    // 16 i32
#define WS_HISTS   16832    // 16*640 u32
#define WS_THRESH  57792    // 16 f32
#define WS_CANDCNT 57856    // 16 i32
#define WS_HISTAGE 57920    // 8192 u32
#define WS_AGETH   90688    // 1 i32
#define WS_AGECNT  90692    // 1 i32
#define WS_AGECAND 90816    // 4096 int2
#define WS_CAND    123584   // 16*2048 int2
#define WS_SCORES  385728   // NM*16 f32 (transposed: scores[m*16+b])
#define WS_ZERO    123584

// ---------------- K1: samples[b][k] = sum_a pos * cls_preds ----------------
__global__ __launch_bounds__(256) void k_cls_sum(const float4* __restrict__ cls4,
                                                 const int* __restrict__ tgt,
                                                 float* __restrict__ samples) {
  int blk = blockIdx.x;
  int b = blk >> 5, chunk = blk & 31;          // 32 chunks of 512 anchors
  int tid = threadIdx.x;
  int kg = tid & 31, sub = tid >> 5;           // kg: float4 group (128 k), sub: 0..7
  float4 acc = make_float4(0.f, 0.f, 0.f, 0.f);
  int a0 = chunk * 512;
  for (int a = a0 + sub; a < a0 + 512; a += 8) {
    int t = tgt[b * NA + a];
    if (t > 0) {
      float4 v = cls4[((size_t)(b * NA + a)) * 32 + kg];
      acc.x += v.x; acc.y += v.y; acc.z += v.z; acc.w += v.w;
    }
  }
  __shared__ float4 red[256];
  red[tid] = acc;
  __syncthreads();
  if (tid < 32) {
    float4 s = red[tid];
    for (int r = 1; r < 8; ++r) {
      float4 v = red[r * 32 + tid];
      s.x += v.x; s.y += v.y; s.z += v.z; s.w += v.w;
    }
    atomicAdd(&samples[b * KD + kg * 4 + 0], s.x);
    atomicAdd(&samples[b * KD + kg * 4 + 1], s.y);
    atomicAdd(&samples[b * KD + kg * 4 + 2], s.z);
    atomicAdd(&samples[b * KD + kg * 4 + 3], s.w);
  }
}

// ---------------- K2: num_pos, loc_loss partial, y = max target ----------------
__global__ __launch_bounds__(256) void k_loc(const float4* __restrict__ lp, const float4* __restrict__ lt,
                                             const int* __restrict__ tgt, float* __restrict__ numpos,
                                             int* __restrict__ ymax, float* __restrict__ locsum) {
  int i = blockIdx.x * 256 + threadIdx.x;
  int b = i >> 14;
  int t = tgt[i];
  float cnt = (t > 0) ? 1.f : 0.f;
  float sl = 0.f;
  if (t > 0) {
    float4 p = lp[i], q = lt[i];
    float d0 = p.x - q.x, d1 = p.y - q.y, d2 = p.z - q.z, d3 = p.w - q.w;
    float a0 = fabsf(d0), a1 = fabsf(d1), a2 = fabsf(d2), a3 = fabsf(d3);
    sl = ((a0 < 1.f) ? 0.5f * d0 * d0 : a0 - 0.5f)
       + ((a1 < 1.f) ? 0.5f * d1 * d1 : a1 - 0.5f)
       + ((a2 < 1.f) ? 0.5f * d2 * d2 : a2 - 0.5f)
       + ((a3 < 1.f) ? 0.5f * d3 * d3 : a3 - 0.5f);
  }
  for (int o = 32; o > 0; o >>= 1) {
    sl += __shfl_down(sl, o);
    cnt += __shfl_down(cnt, o);
    t = max(t, __shfl_down(t, o));
  }
  __shared__ float s_sl[4], s_cnt[4];
  __shared__ int s_t[4];
  int lane = threadIdx.x & 63, w = threadIdx.x >> 6;
  if (lane == 0) { s_sl[w] = sl; s_cnt[w] = cnt; s_t[w] = t; }
  __syncthreads();
  if (threadIdx.x == 0) {
    float SL = s_sl[0] + s_sl[1] + s_sl[2] + s_sl[3];
    float CN = s_cnt[0] + s_cnt[1] + s_cnt[2] + s_cnt[3];
    int T = max(max(s_t[0], s_t[1]), max(s_t[2], s_t[3]));
    atomicAdd(&numpos[b], CN);
    atomicAdd(locsum, SL);
    atomicMax(&ymax[b], T);
  }
}

// ---------------- K3: query = l2norm(samples/num_pos); y, loc_loss out ----------------
__global__ __launch_bounds__(128) void k_query(const float* __restrict__ samples, const float* __restrict__ numpos,
                                               const int* __restrict__ ymax, const float* __restrict__ locsum,
                                               float* __restrict__ qws, float* __restrict__ outf) {
  int tid = threadIdx.x;
  __shared__ float partial[2];
  for (int b = 0; b < NB; ++b) {
    float np_ = numpos[b];
    float v = samples[b * KD + tid] / np_;
    float sq = v * v;
    for (int o = 32; o > 0; o >>= 1) sq += __shfl_down(sq, o);
    if ((tid & 63) == 0) partial[tid >> 6] = sq;
    __syncthreads();
    float nrm = sqrtf(partial[0] + partial[1]);
    float q = v / fmaxf(nrm, 1e-12f);
    qws[b * KD + tid] = q;
    outf[OFF_Q + b * KD + tid] = q;
    __syncthreads();
  }
  if (tid < 16) outf[OFF_Y + tid] = (float)ymax[tid];
  if (tid == 0) {
    float tot = 0.f;
    for (int b = 0; b < NB; ++b) tot += numpos[b];
    outf[OFF_LOC] = locsum[0] / tot;
  }
}

// ---------------- K4: scores = query @ keys.T ; copy keys/values/age to out ----------------
__global__ __launch_bounds__(256) void k_scores(const float4* __restrict__ keys4, const float4* __restrict__ q4,
                                                const int* __restrict__ vals, const float* __restrict__ age,
                                                float* __restrict__ outf, float* __restrict__ scores) {
  __shared__ float4 ql[512];
  int tid = threadIdx.x;
  for (int i = tid; i < 512; i += 256) ql[i] = q4[i];
  __syncthreads();
  int m0 = blockIdx.x * 512;
  float acc[2][16];
#pragma unroll
  for (int s = 0; s < 2; ++s)
#pragma unroll
    for (int b = 0; b < 16; ++b) acc[s][b] = 0.f;
  float2* ok2 = (float2*)(outf + OFF_KEYS);   // 8B-aligned (OFF_KEYS*4 % 16 == 8)
#pragma unroll 2
  for (int j = 0; j < 32; ++j) {
    float4 kv[2];
#pragma unroll
    for (int s = 0; s < 2; ++s) kv[s] = keys4[(size_t)(m0 + s * 256 + tid) * 32 + j];
#pragma unroll
    for (int s = 0; s < 2; ++s) {
      size_t o = (size_t)(m0 + s * 256 + tid) * 64 + j * 2;
      ok2[o]     = make_float2(kv[s].x, kv[s].y);
      ok2[o + 1] = make_float2(kv[s].z, kv[s].w);
    }
#pragma unroll
    for (int b = 0; b < 16; ++b) {
      float4 q = ql[b * 32 + j];
#pragma unroll
      for (int s = 0; s < 2; ++s)
        acc[s][b] += kv[s].x * q.x + kv[s].y * q.y + kv[s].z * q.z + kv[s].w * q.w;
    }
  }
#pragma unroll
  for (int s = 0; s < 2; ++s) {
    int m = m0 + s * 256 + tid;
    float4* st = (float4*)(scores + (size_t)m * 16);
    st[0] = make_float4(acc[s][0], acc[s][1], acc[s][2], acc[s][3]);
    st[1] = make_float4(acc[s][4], acc[s][5], acc[s][6], acc[s][7]);
    st[2] = make_float4(acc[s][8], acc[s][9], acc[s][10], acc[s][11]);
    st[3] = make_float4(acc[s][12], acc[s][13], acc[s][14], acc[s][15]);
    outf[OFF_VALS + m] = (float)vals[m];
    outf[OFF_AGE + m] = age[m] + 1.f;
  }
}

// ---------------- K5: per-row histogram of scores >= 0.0625 (bin = float hi-16 bits) ----------------
__global__ __launch_bounds__(256) void k_hist(const float* __restrict__ scores, u32* __restrict__ ghist) {
  __shared__ u32 h[16 * 640];
  int tid = threadIdx.x;
  for (int i = tid; i < 16 * 640; i += 256) h[i] = 0;
  __syncthreads();
  int m0 = blockIdx.x * 1024;
  for (int s = 0; s < 4; ++s) {
    int m = m0 + s * 256 + tid;
    const float4* sc = (const float4*)(scores + (size_t)m * 16);
#pragma unroll
    for (int g = 0; g < 4; ++g) {
      float4 v = sc[g];
      float fv[4] = {v.x, v.y, v.z, v.w};
#pragma unroll
      for (int c = 0; c < 4; ++c) {
        float f = fv[c];
        if (f >= 0.0625f) {
          u32 u = __float_as_uint(f);
          int bin = (int)(u >> 16) - 0x3D80;
          if (bin > 639) bin = 639;
          atomicAdd(&h[(g * 4 + c) * 640 + bin], 1u);
        }
      }
    }
  }
  __syncthreads();
  for (int i = tid; i < 16 * 640; i += 256) {
    u32 v = h[i];
    if (v) atomicAdd(&ghist[i], v);
  }
}

// ---------------- K6: per-row threshold value from histogram ----------------
__global__ void k_scan(const u32* __restrict__ ghist, float* __restrict__ thresh) {
  int b = threadIdx.x;
  if (b < 16) {
    u32 cum = 0;
    int T = 0;
    for (int i = 639; i >= 0; --i) {
      cum += ghist[b * 640 + i];
      if (cum >= 256) { T = i; break; }
    }
    thresh[b] = __uint_as_float(((u32)(T + 0x3D80)) << 16);
  }
}

// ---------------- K7: gather candidates >= threshold ----------------
__global__ __launch_bounds__(256) void k_gather(const float* __restrict__ scores, const float* __restrict__ thresh,
                                                int* __restrict__ cnt, int2* __restrict__ cand) {
  __shared__ float th[16];
  int tid = threadIdx.x;
  if (tid < 16) th[tid] = thresh[tid];
  __syncthreads();
  int m0 = blockIdx.x * 1024;
  for (int s = 0; s < 4; ++s) {
    int m = m0 + s * 256 + tid;
    const float4* sc = (const float4*)(scores + (size_t)m * 16);
#pragma unroll
    for (int g = 0; g < 4; ++g) {
      float4 v = sc[g];
      float fv[4] = {v.x, v.y, v.z, v.w};
#pragma unroll
      for (int c = 0; c < 4; ++c) {
        int b = g * 4 + c;
        float f = fv[c];
        if (f >= th[b]) {
          int p = atomicAdd(&cnt[b], 1);
          if (p < 2048) cand[b * 2048 + p] = make_int2(__float_as_int(f), m);
        }
      }
    }
  }
}

// ---------------- K8: per-row exact top-256 (bitonic), softmax, margin loss ----------------
__global__ __launch_bounds__(256) void k_topk(const int2* __restrict__ cand, const int* __restrict__ cnt,
                                              const int* __restrict__ vals, const int* __restrict__ ymax,
                                              float* __restrict__ outf, float* __restrict__ rowloss,
                                              int* __restrict__ yhatidx, int* __restrict__ result) {
  int b = blockIdx.x, tid = threadIdx.x;
  __shared__ u64 sk[2048];
  __shared__ float rb[256];
  __shared__ int sidx0;
  int nc = cnt[b];
  if (nc > 2048) nc = 2048;
  for (int i = tid; i < 2048; i += 256) {
    u64 key = 0;
    if (i < nc) {
      int2 c = cand[b * 2048 + i];
      key = ((u64)(u32)c.x << 32) | (u32)(~(u32)c.y);  // score desc, idx asc
    }
    sk[i] = key;
  }
  __syncthreads();
  for (int k2 = 2; k2 <= 2048; k2 <<= 1)
    for (int j2 = k2 >> 1; j2 > 0; j2 >>= 1) {
      for (int i = tid; i < 2048; i += 256) {
        int ix = i ^ j2;
        if (ix > i) {
          u64 x = sk[i], y = sk[ix];
          bool sw = ((i & k2) == 0) ? (x < y) : (x > y);  // descending
          if (sw) { sk[i] = y; sk[ix] = x; }
        }
      }
      __syncthreads();
    }
  int y = ymax[b];
  u64 kk = sk[tid];
  float c_ = __uint_as_float((u32)(kk >> 32));
  int id = (int)(~(u32)(kk & 0xFFFFFFFFull));
  id = min(max(id, 0), NM - 1);
  int vv = vals[id];
  int mk = (vv == y) ? 1 : 0;
  if (tid == 0) sidx0 = id;
  float mx = __uint_as_float((u32)(sk[0] >> 32));
  float e = expf(c_ - mx);
  rb[tid] = e; __syncthreads();
  for (int o = 128; o > 0; o >>= 1) { if (tid < o) rb[tid] += rb[tid + o]; __syncthreads(); }
  float esum = rb[0]; __syncthreads();
  outf[OFF_SM + b * 256 + tid] = e / esum;
  rb[tid] = c_ * (float)mk; __syncthreads();
  for (int o = 128; o > 0; o >>= 1) { if (tid < o) rb[tid] = fmaxf(rb[tid], rb[tid + o]); __syncthreads(); }
  float pmax = rb[0]; __syncthreads();
  rb[tid] = c_ * (float)(1 - mk); __syncthreads();
  for (int o = 128; o > 0; o >>= 1) { if (tid < o) rb[tid] = fmaxf(rb[tid], rb[tid + o]); __syncthreads(); }
  float nmax = rb[0]; __syncthreads();
  rb[tid] = (float)mk; __syncthreads();
  for (int o = 128; o > 0; o >>= 1) { if (tid < o) rb[tid] += rb[tid + o]; __syncthreads(); }
  float msum = rb[0];
  if (tid == 0) {
    float pos = (msum > 0.f) ? pmax : 0.f;
    rowloss[b] = fmaxf(nmax - pos + 0.1f, 0.f);
    int yh = vals[sidx0];
    yhatidx[b] = sidx0;
    result[b] = (yh == y) ? 1 : 0;
    outf[OFF_YHAT + b] = (float)yh;
  }
}

// ---------------- K9: correct-prediction key refresh (serial b, last-wins) + cls_loss ----------------
__global__ __launch_bounds__(128) void k_corr(const float* __restrict__ keys, const float* __restrict__ qws,
                                              const float* __restrict__ rowloss, const int* __restrict__ yhatidx,
                                              const int* __restrict__ result, float* __restrict__ outf) {
  int tid = threadIdx.x;
  __shared__ float partial[2];
  if (tid == 0) {
    float sum = 0.f;
    for (int b = 0; b < NB; ++b) sum += rowloss[b];
    outf[OFF_CLS] = sum * (1.f / 16.f);
  }
  for (int b = 0; b < NB; ++b) {
    if (result[b]) {
      int dest = yhatidx[b];
      float v = keys[(size_t)dest * KD + tid] + qws[b * KD + tid];
      float sq = v * v;
      for (int o = 32; o > 0; o >>= 1) sq += __shfl_down(sq, o);
      if ((tid & 63) == 0) partial[tid >> 6] = sq;
      __syncthreads();
      float nrm = sqrtf(partial[0] + partial[1]);
      outf[OFF_KEYS + (size_t)dest * KD + tid] = v / fmaxf(nrm, 1e-12f);
      if (tid == 0) outf[OFF_AGE + dest] = 0.f;
    }
    __syncthreads();
  }
}

__device__ __forceinline__ int age_bin(float an) {
  // deterministic (no-contract) binning, identical in hist and gather kernels
  float x = __fmul_rn(__fadd_rn(an, 8.f), 8192.f / 120.f);
  int bin = (int)x;
  return min(max(bin, 0), 8191);
}

// ---------------- K10a: histogram of age_noisy ----------------
__global__ __launch_bounds__(256) void k_hage(const float* __restrict__ oage, const float* __restrict__ noise,
                                              u32* __restrict__ hist) {
  __shared__ u32 h[8192];
  int tid = threadIdx.x;
  for (int i = tid; i < 8192; i += 256) h[i] = 0;
  __syncthreads();
  int m0 = blockIdx.x * 4096;
  for (int s = 0; s < 16; ++s) {
    int m = m0 + s * 256 + tid;
    float an = oage[m] + (noise[m] * 2.f - 1.f) * 8.f;
    atomicAdd(&h[age_bin(an)], 1u);
  }
  __syncthreads();
  for (int i = tid; i < 8192; i += 256) {
    u32 v = h[i];
    if (v) atomicAdd(&hist[i], v);
  }
}

// ---------------- K10b: threshold bin for top-16 ----------------
__global__ void k_scan_age(const u32* __restrict__ hist, int* __restrict__ T) {
  if (threadIdx.x == 0) {
    u32 cum = 0;
    int t = 0;
    for (int i = 8191; i >= 0; --i) {
      cum += hist[i];
      if (cum >= 16) { t = i; break; }
    }
    *T = t;
  }
}

// ---------------- K10c: gather age candidates ----------------
__global__ __launch_bounds__(256) void k_gage(const float* __restrict__ oage, const float* __restrict__ noise,
                                              const int* __restrict__ T, int* __restrict__ cnt,
                                              int2* __restrict__ cand) {
  int tb = *T;
  int tid = threadIdx.x;
  int m0 = blockIdx.x * 1024;
  for (int s = 0; s < 4; ++s) {
    int m = m0 + s * 256 + tid;
    float an = oage[m] + (noise[m] * 2.f - 1.f) * 8.f;
    if (age_bin(an) >= tb) {
      int p = atomicAdd(cnt, 1);
      if (p < 4096) {
        u32 u = __float_as_uint(an);
        u = (u & 0x80000000u) ? ~u : (u | 0x80000000u);  // order-preserving flip
        cand[p] = make_int2((int)u, m);
      }
    }
  }
}

// ---------------- K11: oldest top-16, incorrect-prediction inserts ----------------
__global__ __launch_bounds__(256) void k_inc(const int* __restrict__ cnt, const int2* __restrict__ cand,
                                             const float* __restrict__ qws, const int* __restrict__ ymax,
                                             const int* __restrict__ result, float* __restrict__ outf) {
  __shared__ u64 sk[2048];
  __shared__ int oldest[16];
  __shared__ int dest[16];
  int tid = threadIdx.x;
  int nc = *cnt;
  if (nc > 2048) nc = 2048;
  for (int i = tid; i < 2048; i += 256) {
    u64 key = 0;
    if (i < nc) {
      int2 c = cand[i];
      key = ((u64)(u32)c.x << 32) | (u32)(~(u32)c.y);
    }
    sk[i] = key;
  }
  __syncthreads();
  for (int k2 = 2; k2 <= 2048; k2 <<= 1)
    for (int j2 = k2 >> 1; j2 > 0; j2 >>= 1) {
      for (int i = tid; i < 2048; i += 256) {
        int ix = i ^ j2;
        if (ix > i) {
          u64 x = sk[i], y = sk[ix];
          bool sw = ((i & k2) == 0) ? (x < y) : (x > y);
          if (sw) { sk[i] = y; sk[ix] = x; }
        }
      }
      __syncthreads();
    }
  if (tid < 16) {
    int id = (int)(~(u32)(sk[tid] & 0xFFFFFFFFull));
    oldest[tid] = min(max(id, 0), NM - 1);
  }
  __syncthreads();
  if (tid == 0) {
    int r = 0;
    for (int b = 0; b < NB; ++b) {
      if (!result[b]) { dest[b] = oldest[min(r, 15)]; r++; }
      else dest[b] = -1;
    }
  }
  __syncthreads();
  for (int b = 0; b < NB; ++b) {
    int d = dest[b];
    if (d >= 0) {
      if (tid < KD) outf[OFF_KEYS + (size_t)d * KD + tid] = qws[b * KD + tid];
      if (tid == 0) {
        outf[OFF_VALS + d] = (float)ymax[b];
        outf[OFF_AGE + d] = 0.f;
      }
    }
  }
}

extern "C" void kernel_launch(void* const* d_in, const int* in_sizes, int n_in,
                              void* d_out, int out_size, void* d_ws, size_t ws_size,
                              hipStream_t stream) {
  const float4* lp   = (const float4*)d_in[0];
  const float4* cls4 = (const float4*)d_in[1];
  const float4* lt   = (const float4*)d_in[2];
  const int* tgt     = (const int*)d_in[3];
  const float* keys  = (const float*)d_in[4];
  const int* vals    = (const int*)d_in[5];
  const float* age   = (const float*)d_in[6];
  const float* noise = (const float*)d_in[7];
  float* outf = (float*)d_out;
  char* ws = (char*)d_ws;

  hipMemsetAsync(ws, 0, WS_ZERO, stream);
  k_cls_sum<<<512, 256, 0, stream>>>(cls4, tgt, (float*)(ws + WS_SAMPLES));
  k_loc<<<1024, 256, 0, stream>>>(lp, lt, tgt, (float*)(ws + WS_NUMPOS),
                                  (int*)(ws + WS_YMAX), (float*)(ws + WS_LOCSUM));
  k_query<<<1, 128, 0, stream>>>((const float*)(ws + WS_SAMPLES), (const float*)(ws + WS_NUMPOS),
                                 (const int*)(ws + WS_YMAX), (const float*)(ws + WS_LOCSUM),
                                 (float*)(ws + WS_QUERY), outf);
  k_scores<<<1024, 256, 0, stream>>>((const float4*)keys, (const float4*)(ws + WS_QUERY),
                                     vals, age, outf, (float*)(ws + WS_SCORES));
  k_hist<<<512, 256, 0, stream>>>((const float*)(ws + WS_SCORES), (u32*)(ws + WS_HISTS));
  k_scan<<<1, 64, 0, stream>>>((const u32*)(ws + WS_HISTS), (float*)(ws + WS_THRESH));
  k_gather<<<512, 256, 0, stream>>>((const float*)(ws + WS_SCORES), (const float*)(ws + WS_THRESH),
                                    (int*)(ws + WS_CANDCNT), (int2*)(ws + WS_CAND));
  k_topk<<<16, 256, 0, stream>>>((const int2*)(ws + WS_CAND), (const int*)(ws + WS_CANDCNT),
                                 vals, (const int*)(ws + WS_YMAX), outf, (float*)(ws + WS_ROWLOSS),
                                 (int*)(ws + WS_YHATIDX), (int*)(ws + WS_RESULT));
  k_corr<<<1, 128, 0, stream>>>(keys, (const float*)(ws + WS_QUERY), (const float*)(ws + WS_ROWLOSS),
                                (const int*)(ws + WS_YHATIDX), (const int*)(ws + WS_RESULT), outf);
  k_hage<<<128, 256, 0, stream>>>(outf + OFF_AGE, noise, (u32*)(ws + WS_HISTAGE));
  k_scan_age<<<1, 64, 0, stream>>>((const u32*)(ws + WS_HISTAGE), (int*)(ws + WS_AGETH));
  k_gage<<<512, 256, 0, stream>>>(outf + OFF_AGE, noise, (const int*)(ws + WS_AGETH),
                                  (int*)(ws + WS_AGECNT), (int2*)(ws + WS_AGECAND));
  k_inc<<<1, 256, 0, stream>>>((const int*)(ws + WS_AGECNT), (const int2*)(ws + WS_AGECAND),
                               (const float*)(ws + WS_QUERY), (const int*)(ws + WS_YMAX),
                               (const int*)(ws + WS_RESULT), outf);
}